// Round 3
// baseline (928.517 us; speedup 1.0000x reference)
//
#include <hip/hip_runtime.h>

#define S    8192
#define Dm   4096
#define E    64
#define CAP  128

#define CW_OFF 1
#define DM_OFF (1 + (size_t)S*E*CAP)
#define EC_OFF (1 + 2*(size_t)S*E*CAP)

// ---------------- K0: pack wg[64][4096] -> wt2[k/4][e][4] -------------------
// element (k,e) -> wt2[(k>>2)*256 + e*4 + (k&3)]
__global__ void k0_pack(const float* __restrict__ wg, float* __restrict__ wt2) {
    const int g  = blockIdx.x * 256 + threadIdx.x;  // 65536 total
    const int e  = g & 63;
    const int k4 = g >> 6;                          // 0..1023
    const float4 v = *(const float4*)(wg + (size_t)e * Dm + k4 * 4);
    *(float4*)(wt2 + (size_t)k4 * 256 + e * 4) = v; // coalesced 1KB/wave store
}

// ---------------- K1: fused gate GEMM + softmax + argmax --------------------
// block = 4 waves, 16 tokens; lane = expert; wave w covers k in [1024w,1024w+1024)
// x via wave-uniform scalar loads (SGPR operand of v_fma), W via coalesced
// per-lane float4 (reused across 16 tokens in registers).
__global__ __launch_bounds__(256, 2)
void k1_fused(const float* __restrict__ x, const float* __restrict__ wt2,
              float* __restrict__ gate_val, int* __restrict__ idx1,
              int* __restrict__ counts, float* __restrict__ me_sum) {
    __shared__ float red[4 * 16 * 64];   // 16 KB
    const int tid  = threadIdx.x;
    const int lane = tid & 63;
    const int wv   = __builtin_amdgcn_readfirstlane(tid >> 6);  // force uniform
    const int tok0 = blockIdx.x * 16;

    const float* xp = x   + ((size_t)tok0 << 12) + ((size_t)wv << 10); // uniform base
    const float* wp = wt2 + ((size_t)wv << 16) + (lane << 2);

    float acc[16];
    #pragma unroll
    for (int t = 0; t < 16; t++) acc[t] = 0.f;

    float4 w4 = *(const float4*)(wp);
    for (int k = 0; k < 1024; k += 4) {
        const float4 w4n = *(const float4*)(wp + 256);  // prefetch (1KB overread at end: padded)
        #pragma unroll
        for (int t = 0; t < 16; t++) {
            const float4 xv = *(const float4*)(xp + (size_t)t * Dm + k); // s_load_dwordx4
            acc[t] = fmaf(xv.x, w4.x, acc[t]);
            acc[t] = fmaf(xv.y, w4.y, acc[t]);
            acc[t] = fmaf(xv.z, w4.z, acc[t]);
            acc[t] = fmaf(xv.w, w4.w, acc[t]);
        }
        w4 = w4n;
        wp += 256;
    }

    // combine 4 k-partials per (token, expert) via LDS
    #pragma unroll
    for (int t = 0; t < 16; t++) red[(wv * 16 + t) * 64 + lane] = acc[t];
    __syncthreads();

    float meg = 0.f;
    #pragma unroll
    for (int j = 0; j < 4; j++) {
        const int tt = j * 4 + wv;    // wave wv handles tokens {wv, wv+4, wv+8, wv+12}
        float p = red[(0 * 16 + tt) * 64 + lane] + red[(1 * 16 + tt) * 64 + lane]
                + red[(2 * 16 + tt) * 64 + lane] + red[(3 * 16 + tt) * 64 + lane];
        // argmax (max value, lowest index on ties) — matches jnp.argmax
        float v = p; int im = lane;
        #pragma unroll
        for (int off = 1; off < 64; off <<= 1) {
            float ov = __shfl_xor(v, off, 64);
            int   oi = __shfl_xor(im, off, 64);
            if (ov > v || (ov == v && oi < im)) { v = ov; im = oi; }
        }
        float g = __expf(p - v);
        float ssum = g;
        #pragma unroll
        for (int off = 1; off < 64; off <<= 1) ssum += __shfl_xor(ssum, off, 64);
        meg += g / ssum;
        if (lane == 0) {
            gate_val[tok0 + tt] = 1.0f / ssum;   // gate of selected expert
            idx1[tok0 + tt] = im;
            atomicAdd(&counts[im], 1);
        }
    }
    __syncthreads();                 // all reads of red done
    red[wv * 64 + lane] = meg;       // reuse LDS for me partial
    __syncthreads();
    if (wv == 0)
        atomicAdd(&me_sum[lane],
                  red[lane] + red[64 + lane] + red[128 + lane] + red[192 + lane]);
}

// ---------------- K2: per-expert capacity selection + scatter ----------------
__device__ __forceinline__ int block_reduce_sum(int v, int* tmp4, int tid) {
    #pragma unroll
    for (int off = 1; off < 64; off <<= 1) v += __shfl_xor(v, off, 64);
    __syncthreads();
    if ((tid & 63) == 0) tmp4[tid >> 6] = v;
    __syncthreads();
    return tmp4[0] + tmp4[1] + tmp4[2] + tmp4[3];
}

__device__ __forceinline__ int block_scan_incl(int val, int* a, int* b, int tid, int* total) {
    __syncthreads();
    a[tid] = val;
    __syncthreads();
    int* src = a; int* dst = b;
    #pragma unroll
    for (int off = 1; off < 256; off <<= 1) {
        int v = src[tid];
        if (tid >= off) v += src[tid - off];
        dst[tid] = v;
        __syncthreads();
        int* t = src; src = dst; dst = t;
    }
    *total = src[255];
    return src[tid];
}

__global__ __launch_bounds__(256, 1)
void k2_select(const int* __restrict__ idx1, const float* __restrict__ gate_val,
               const float* __restrict__ noise, const int* __restrict__ counts,
               const float* __restrict__ me_sum, float* __restrict__ out) {
    const int e = blockIdx.x;
    const int tid = threadIdx.x;
    __shared__ int idx_s[S];            // 32 KB, coalesced-staged
    __shared__ unsigned short l_tok[S]; // 16 KB
    __shared__ float l_ns[S];           // 32 KB
    __shared__ int sa[256], sb[256];
    __shared__ int tmp4[4];

    for (int i = tid; i < S; i += 256) idx_s[i] = idx1[i];
    __syncthreads();

    // pass 1: count matches in my ordered chunk of 32 tokens (int4 LDS reads)
    int cnt = 0;
    #pragma unroll
    for (int j4 = 0; j4 < 8; j4++) {
        const int4 q = *(const int4*)&idx_s[tid * 32 + j4 * 4];
        cnt += (q.x == e) + (q.y == e) + (q.z == e) + (q.w == e);
    }
    int total_n;
    int incl = block_scan_incl(cnt, sa, sb, tid, &total_n);
    int pos = incl - cnt;
    const int n = total_n;
    // pass 2: ordered compaction (list is token-index ordered)
    #pragma unroll
    for (int j4 = 0; j4 < 8; j4++) {
        const int4 q = *(const int4*)&idx_s[tid * 32 + j4 * 4];
        const int qv[4] = {q.x, q.y, q.z, q.w};
        #pragma unroll
        for (int u = 0; u < 4; u++) {
            const int s = tid * 32 + j4 * 4 + u;
            if (qv[u] == e) {
                l_tok[pos] = (unsigned short)s;
                l_ns[pos]  = noise[(size_t)s * E + e];
                pos++;
            }
        }
    }
    __syncthreads();

    if (tid == 0) out[EC_OFF + e] = (float)n;   // exp_counts (pre-capacity)

    // find 128th-largest noise value via binary search on positive-float bits
    unsigned int V = 0u;
    if (n > CAP) {
        unsigned int lo = 0u, hi = 0x3F800000u;   // [0, 1.0)
        while (hi - lo > 1u) {
            const unsigned int mid = (lo + hi) >> 1;
            int c = 0;
            for (int i2 = tid; i2 < n; i2 += 256)
                c += (__float_as_uint(l_ns[i2]) >= mid);
            const int cge = block_reduce_sum(c, tmp4, tid);
            if (cge >= CAP) lo = mid; else hi = mid;
        }
        V = lo;
    }

    // per-thread ordered chunk of the list
    const int m = (n + 255) >> 8;
    const int i_begin = min(n, tid * m);
    const int i_end   = min(n, i_begin + m);
    int gt_l = 0, eq_l = 0;
    for (int i2 = i_begin; i2 < i_end; i2++) {
        const unsigned int b = __float_as_uint(l_ns[i2]);
        gt_l += (b > V); eq_l += (b == V);
    }
    int tot_gt, tot_eq;
    const int incl_gt = block_scan_incl(gt_l, sa, sb, tid, &tot_gt);
    (void)incl_gt;
    const int incl_eq = block_scan_incl(eq_l, sa, sb, tid, &tot_eq);
    const int eq_excl = incl_eq - eq_l;
    const int take_eq = CAP - tot_gt;   // ties -> lowest token index (jax top_k stable)
    const int sel_l = gt_l + max(0, min(eq_l, take_eq - eq_excl));
    int tot_sel;
    const int incl_sel = block_scan_incl(sel_l, sa, sb, tid, &tot_sel);
    int slot = incl_sel - sel_l;
    int eq_seen = eq_excl;
    for (int i2 = i_begin; i2 < i_end; i2++) {
        const unsigned int b = __float_as_uint(l_ns[i2]);
        bool sel;
        if (b > V) sel = true;
        else if (b == V) { sel = (eq_seen < take_eq); eq_seen++; }
        else sel = false;
        if (sel) {
            const int tok = l_tok[i2];
            const float g = gate_val[tok];
            const size_t off = (size_t)tok * (E * CAP) + (size_t)e * CAP + slot;
            out[CW_OFF + off] = g;
            out[DM_OFF + off] = 1.0f;
            slot++;
        }
    }

    // l_aux (counts exact ints; me atomic order error ~1e-7, scalar)
    if (e == 0 && tid < 64) {
        float la = (me_sum[tid] / (float)S) * ((float)counts[tid] / (float)S);
        #pragma unroll
        for (int off = 1; off < 64; off <<= 1) la += __shfl_xor(la, off, 64);
        if (tid == 0) out[0] = la * (float)E;
    }
}

extern "C" void kernel_launch(void* const* d_in, const int* in_sizes, int n_in,
                              void* d_out, int out_size, void* d_ws, size_t ws_size,
                              hipStream_t stream) {
    const float* x     = (const float*)d_in[0];
    const float* wg    = (const float*)d_in[1];
    const float* noise = (const float*)d_in[2];
    float* out = (float*)d_out;
    float* ws  = (float*)d_ws;

    float* gate_val = ws;                   // 8192 f32
    int*   idx1     = (int*)(ws + 8192);    // 8192 i32
    int*   counts   = (int*)(ws + 16384);   // 64 i32
    float* me_sum   = ws + 16448;           // 64 f32
    float* wt2      = ws + 16512;           // 262144 f32 (+256 pad for prefetch overread)

    hipMemsetAsync(counts, 0, 128 * sizeof(int), stream);      // counts + me_sum
    hipMemsetAsync(out, 0, (size_t)out_size * sizeof(float), stream);
    k0_pack <<<dim3(256),  dim3(256), 0, stream>>>(wg, wt2);
    k1_fused<<<dim3(S/16), dim3(256), 0, stream>>>(x, wt2, gate_val, idx1, counts, me_sum);
    k2_select<<<dim3(E),   dim3(256), 0, stream>>>(idx1, gate_val, noise, counts, me_sum, out);
}

// Round 4
// 798.897 us; speedup vs baseline: 1.1622x; 1.1622x over previous
//
#include <hip/hip_runtime.h>

#define S    8192
#define Dm   4096
#define E    64
#define CAP  128
#define CCH  32          // split-K chunks
#define KC   (Dm/CCH)    // 128 k per chunk
#define TBv  512         // tokens per K1 block (4 waves x 2 tokens/lane x 64)
#define KSUB 32          // k sub-tile staged in LDS
#define XSTR 33          // xs row stride: bank = (lane+kk)%32, conflict-free

#define CW_OFF 1
#define DM_OFF (1 + (size_t)S*E*CAP)
#define EC_OFF (1 + 2*(size_t)S*E*CAP)

// ---------------- K0: transpose wg[64][4096] -> wt2[k][e] -------------------
__global__ void k0_transpose(const float* __restrict__ wg, float* __restrict__ wt2) {
    const int e  = blockIdx.x >> 2;
    const int kb = (blockIdx.x & 3) * 1024;
    const int t  = threadIdx.x;
    const float4 v = *(const float4*)(wg + (size_t)e * Dm + kb + t * 4);
    wt2[(size_t)(kb + t*4 + 0) * E + e] = v.x;
    wt2[(size_t)(kb + t*4 + 1) * E + e] = v.y;
    wt2[(size_t)(kb + t*4 + 2) * E + e] = v.z;
    wt2[(size_t)(kb + t*4 + 3) * E + e] = v.w;
}

// ---------------- K1: partial logits. token=lane (2/lane), acc[128], --------
// ---------------- W via LDS b128 uniform broadcast, x via LDS b32 -----------
__global__ __launch_bounds__(256, 2)
void k1_partial(const float* __restrict__ x, const float* __restrict__ wt2,
                float* __restrict__ part) {
    __shared__ float  xs[TBv * XSTR];      // 67.6 KB
    __shared__ float4 ws4[KSUB * 16];      // 8 KB, [kk][e4]
    const int tb  = blockIdx.x >> 5;       // 0..15 token block
    const int c   = blockIdx.x & 31;       // 0..31 k chunk
    const int tid = threadIdx.x;
    const int lane = tid & 63;
    const int wv   = tid >> 6;
    const int k0 = c * KC;

    const int ta = wv * 128 + lane;        // token a (block-local); token b = ta+64
    const int xa_base = ta * XSTR;
    const int xb_base = xa_base + 64 * XSTR;

    float acca[64], accb[64];
    #pragma unroll
    for (int e = 0; e < 64; e++) { acca[e] = 0.f; accb[e] = 0.f; }

    const int r0 = tid >> 3;               // 0..31 (row group for x staging)
    const int c4 = tid & 7;                // 0..7  (float4 col)

    for (int su = 0; su < KC / KSUB; su++) {
        const int ks0 = k0 + su * KSUB;
        // stage x tile: 512 rows x 32 k, coalesced float4 loads, b32 stores
        #pragma unroll
        for (int i = 0; i < 16; i++) {
            const int row = i * 32 + r0;
            const float4 v = *(const float4*)(x + (size_t)(tb*TBv + row) * Dm + ks0 + c4*4);
            float* p = xs + row * XSTR + c4 * 4;
            p[0] = v.x; p[1] = v.y; p[2] = v.z; p[3] = v.w;
        }
        // stage W tile: 32 k x 64 e contiguous, b128
        {
            const float* wsrc = wt2 + (size_t)ks0 * E;
            ws4[tid]       = *(const float4*)(wsrc + tid * 4);
            ws4[tid + 256] = *(const float4*)(wsrc + 1024 + tid * 4);
        }
        __syncthreads();
        #pragma unroll 2
        for (int kk = 0; kk < KSUB; kk++) {
            const float xa = xs[xa_base + kk];
            const float xb = xs[xb_base + kk];
            #pragma unroll
            for (int e4 = 0; e4 < 16; e4++) {
                const float4 w = ws4[kk * 16 + e4];   // uniform -> LDS broadcast
                acca[e4*4+0] = fmaf(xa, w.x, acca[e4*4+0]);
                acca[e4*4+1] = fmaf(xa, w.y, acca[e4*4+1]);
                acca[e4*4+2] = fmaf(xa, w.z, acca[e4*4+2]);
                acca[e4*4+3] = fmaf(xa, w.w, acca[e4*4+3]);
                accb[e4*4+0] = fmaf(xb, w.x, accb[e4*4+0]);
                accb[e4*4+1] = fmaf(xb, w.y, accb[e4*4+1]);
                accb[e4*4+2] = fmaf(xb, w.z, accb[e4*4+2]);
                accb[e4*4+3] = fmaf(xb, w.w, accb[e4*4+3]);
            }
        }
        __syncthreads();
    }
    // part[c][s][e]: per-wave fully coalesced 16 KB burst
    const size_t tok_a = (size_t)tb * TBv + ta;
    float* pa = part + ((size_t)c * S + tok_a) * E;
    float* pb = pa + 64 * E;
    #pragma unroll
    for (int e4 = 0; e4 < 16; e4++) {
        *(float4*)(pa + e4*4) = make_float4(acca[e4*4], acca[e4*4+1], acca[e4*4+2], acca[e4*4+3]);
        *(float4*)(pb + e4*4) = make_float4(accb[e4*4], accb[e4*4+1], accb[e4*4+2], accb[e4*4+3]);
    }
}

// ---------------- K1b: reduce partials, softmax, argmax, me atomics ----------
__global__ __launch_bounds__(256, 1)
void k1b_softmax(const float* __restrict__ part, float* __restrict__ gate_val,
                 int* __restrict__ idx1, int* __restrict__ counts,
                 float* __restrict__ me_sum) {
    const int tid = threadIdx.x, wv = tid >> 6, ln = tid & 63;
    const int token = blockIdx.x * 4 + wv;
    float p = 0.f;
    #pragma unroll
    for (int c = 0; c < CCH; c++) p += part[((size_t)c * S + token) * E + ln];
    // argmax (max value, lowest index on ties) — matches jnp.argmax
    float v = p; int i = ln;
    #pragma unroll
    for (int off = 1; off < 64; off <<= 1) {
        float ov = __shfl_xor(v, off, 64);
        int   oi = __shfl_xor(i, off, 64);
        if (ov > v || (ov == v && oi < i)) { v = ov; i = oi; }
    }
    float g = __expf(p - v);
    float ssum = g;
    #pragma unroll
    for (int off = 1; off < 64; off <<= 1) ssum += __shfl_xor(ssum, off, 64);
    const float gate = g / ssum;
    __shared__ float gs[4][64];
    gs[wv][ln] = gate;
    __syncthreads();
    if (tid < 64)
        atomicAdd(&me_sum[tid], gs[0][tid] + gs[1][tid] + gs[2][tid] + gs[3][tid]);
    if (ln == 0) {
        gate_val[token] = 1.0f / ssum;
        idx1[token] = i;
        atomicAdd(&counts[i], 1);
    }
}

// ---------------- K2: per-expert capacity selection + scatter ----------------
__device__ __forceinline__ int block_reduce_sum(int v, int* tmp4, int tid) {
    #pragma unroll
    for (int off = 1; off < 64; off <<= 1) v += __shfl_xor(v, off, 64);
    __syncthreads();
    if ((tid & 63) == 0) tmp4[tid >> 6] = v;
    __syncthreads();
    return tmp4[0] + tmp4[1] + tmp4[2] + tmp4[3];
}

__device__ __forceinline__ int block_scan_incl(int val, int* a, int* b, int tid, int* total) {
    __syncthreads();
    a[tid] = val;
    __syncthreads();
    int* src = a; int* dst = b;
    #pragma unroll
    for (int off = 1; off < 256; off <<= 1) {
        int v = src[tid];
        if (tid >= off) v += src[tid - off];
        dst[tid] = v;
        __syncthreads();
        int* t = src; src = dst; dst = t;
    }
    *total = src[255];
    return src[tid];
}

__global__ __launch_bounds__(256, 1)
void k2_select(const int* __restrict__ idx1, const float* __restrict__ gate_val,
               const float* __restrict__ noise, const int* __restrict__ counts,
               const float* __restrict__ me_sum, float* __restrict__ out) {
    const int e = blockIdx.x;
    const int tid = threadIdx.x;
    __shared__ int idx_s[S];
    __shared__ unsigned short l_tok[S];
    __shared__ float l_ns[S];
    __shared__ int sa[256], sb[256];
    __shared__ int tmp4[4];

    for (int i = tid; i < S; i += 256) idx_s[i] = idx1[i];
    __syncthreads();

    int cnt = 0;
    #pragma unroll
    for (int j4 = 0; j4 < 8; j4++) {
        const int4 q = *(const int4*)&idx_s[tid * 32 + j4 * 4];
        cnt += (q.x == e) + (q.y == e) + (q.z == e) + (q.w == e);
    }
    int total_n;
    int incl = block_scan_incl(cnt, sa, sb, tid, &total_n);
    int pos = incl - cnt;
    const int n = total_n;
    #pragma unroll
    for (int j4 = 0; j4 < 8; j4++) {
        const int4 q = *(const int4*)&idx_s[tid * 32 + j4 * 4];
        const int qv[4] = {q.x, q.y, q.z, q.w};
        #pragma unroll
        for (int u = 0; u < 4; u++) {
            const int s = tid * 32 + j4 * 4 + u;
            if (qv[u] == e) {
                l_tok[pos] = (unsigned short)s;
                l_ns[pos]  = noise[(size_t)s * E + e];
                pos++;
            }
        }
    }
    __syncthreads();

    if (tid == 0) out[EC_OFF + e] = (float)n;

    unsigned int V = 0u;
    if (n > CAP) {
        unsigned int lo = 0u, hi = 0x3F800000u;
        while (hi - lo > 1u) {
            const unsigned int mid = (lo + hi) >> 1;
            int c = 0;
            for (int i2 = tid; i2 < n; i2 += 256)
                c += (__float_as_uint(l_ns[i2]) >= mid);
            const int cge = block_reduce_sum(c, tmp4, tid);
            if (cge >= CAP) lo = mid; else hi = mid;
        }
        V = lo;
    }

    const int m = (n + 255) >> 8;
    const int i_begin = min(n, tid * m);
    const int i_end   = min(n, i_begin + m);
    int gt_l = 0, eq_l = 0;
    for (int i2 = i_begin; i2 < i_end; i2++) {
        const unsigned int b = __float_as_uint(l_ns[i2]);
        gt_l += (b > V); eq_l += (b == V);
    }
    int tot_gt, tot_eq;
    const int incl_gt = block_scan_incl(gt_l, sa, sb, tid, &tot_gt);
    (void)incl_gt;
    const int incl_eq = block_scan_incl(eq_l, sa, sb, tid, &tot_eq);
    const int eq_excl = incl_eq - eq_l;
    const int take_eq = CAP - tot_gt;   // ties -> lowest token index (jax top_k stable)
    const int sel_l = gt_l + max(0, min(eq_l, take_eq - eq_excl));
    int tot_sel;
    const int incl_sel = block_scan_incl(sel_l, sa, sb, tid, &tot_sel);
    int slot = incl_sel - sel_l;
    int eq_seen = eq_excl;
    for (int i2 = i_begin; i2 < i_end; i2++) {
        const unsigned int b = __float_as_uint(l_ns[i2]);
        bool sel;
        if (b > V) sel = true;
        else if (b == V) { sel = (eq_seen < take_eq); eq_seen++; }
        else sel = false;
        if (sel) {
            const int tok = l_tok[i2];
            const float g = gate_val[tok];
            const size_t off = (size_t)tok * (E * CAP) + (size_t)e * CAP + slot;
            out[CW_OFF + off] = g;
            out[DM_OFF + off] = 1.0f;
            slot++;
        }
    }

    if (e == 0 && tid < 64) {
        float la = (me_sum[tid] / (float)S) * ((float)counts[tid] / (float)S);
        #pragma unroll
        for (int off = 1; off < 64; off <<= 1) la += __shfl_xor(la, off, 64);
        if (tid == 0) out[0] = la * (float)E;
    }
}

extern "C" void kernel_launch(void* const* d_in, const int* in_sizes, int n_in,
                              void* d_out, int out_size, void* d_ws, size_t ws_size,
                              hipStream_t stream) {
    const float* x     = (const float*)d_in[0];
    const float* wg    = (const float*)d_in[1];
    const float* noise = (const float*)d_in[2];
    float* out = (float*)d_out;
    float* ws  = (float*)d_ws;

    float* gate_val = ws;                   // 8192 f32
    int*   idx1     = (int*)(ws + 8192);    // 8192 i32
    int*   counts   = (int*)(ws + 16384);   // 64 i32
    float* me_sum   = ws + 16448;           // 64 f32
    float* wt2      = ws + 16512;           // 262144 f32
    float* part     = ws + 16512 + 262144;  // 32*8192*64 f32 = 67 MB

    hipMemsetAsync(counts, 0, 128 * sizeof(int), stream);      // counts + me_sum
    hipMemsetAsync(out, 0, (size_t)out_size * sizeof(float), stream);
    k0_transpose<<<dim3(256),  dim3(256), 0, stream>>>(wg, wt2);
    k1_partial  <<<dim3(512),  dim3(256), 0, stream>>>(x, wt2, part);
    k1b_softmax <<<dim3(S/4),  dim3(256), 0, stream>>>(part, gate_val, idx1, counts, me_sum);
    k2_select   <<<dim3(E),    dim3(256), 0, stream>>>(idx1, gate_val, noise, counts, me_sum, out);
}

// Round 5
// 719.910 us; speedup vs baseline: 1.2898x; 1.1097x over previous
//
#include <hip/hip_runtime.h>

#define S    8192
#define Dm   4096
#define E    64
#define CAP  128
#define CCH  16          // split-K chunks
#define KC   (Dm/CCH)    // 256 k per chunk
#define KSUB 32          // k sub-tile staged in LDS
#define XSTR 260         // xs row stride (floats): 16B-aligned, 4-way store conflict only

#define CW_OFF 1
#define DM_OFF (1 + (size_t)S*E*CAP)
#define EC_OFF (1 + 2*(size_t)S*E*CAP)

// ---------------- K0: transpose wg[64][4096] -> wt2[k][e] -------------------
__global__ void k0_transpose(const float* __restrict__ wg, float* __restrict__ wt2) {
    const int e  = blockIdx.x >> 2;
    const int kb = (blockIdx.x & 3) * 1024;
    const int t  = threadIdx.x;
    const float4 v = *(const float4*)(wg + (size_t)e * Dm + kb + t * 4);
    wt2[(size_t)(kb + t*4 + 0) * E + e] = v.x;
    wt2[(size_t)(kb + t*4 + 1) * E + e] = v.y;
    wt2[(size_t)(kb + t*4 + 2) * E + e] = v.z;
    wt2[(size_t)(kb + t*4 + 3) * E + e] = v.w;
}

// ---------------- K1: register-tiled partial GEMM ---------------------------
// block: 256 tokens x 64 experts x KC k. thread: 4 tokens x 16 experts (acc[64]).
// xs transposed [k][token]: a_frag = 1 contiguous ds_read_b128;
// w_frag = 4 broadcast ds_read_b128. ~60 LDS cyc per 128 VALU cyc.
__global__ __launch_bounds__(256, 2)
void k1_partial(const float* __restrict__ x, const float* __restrict__ wt2,
                float* __restrict__ part) {
    __shared__ float  xs[KSUB * XSTR];     // 33.3 KB, [k][token]
    __shared__ float4 ws4[KSUB * 16];      // 8 KB,   [k][e4]
    const int tb  = blockIdx.x >> 4;       // 0..31 token block
    const int c   = blockIdx.x & 15;       // 0..15 k chunk
    const int tid = threadIdx.x;
    const int tg  = tid & 63;              // token group (4 consecutive tokens)
    const int ng  = tid >> 6;              // expert group (16 experts)
    const int k0  = c * KC;

    float acc[64];
    #pragma unroll
    for (int i = 0; i < 64; i++) acc[i] = 0.f;

    const int c4   = tid & 7;              // float4 col in k
    const int trow = tid >> 3;             // 0..31 token row group

    for (int su = 0; su < KC / KSUB; su++) {
        const int ks0 = k0 + su * KSUB;
        // stage x: 256 tokens x 32 k, transposed into xs[k][token]
        #pragma unroll
        for (int i = 0; i < 8; i++) {
            const int token = i * 32 + trow;
            const float4 v = *(const float4*)(x + (size_t)(tb*256 + token) * Dm + ks0 + c4*4);
            xs[(c4*4+0)*XSTR + token] = v.x;
            xs[(c4*4+1)*XSTR + token] = v.y;
            xs[(c4*4+2)*XSTR + token] = v.z;
            xs[(c4*4+3)*XSTR + token] = v.w;
        }
        // stage W: 32 k x 64 e, coalesced
        {
            const float4* wsrc = (const float4*)(wt2 + (size_t)ks0 * E);
            ws4[tid]       = wsrc[tid];
            ws4[tid + 256] = wsrc[tid + 256];
        }
        __syncthreads();
        #pragma unroll 2
        for (int kk = 0; kk < KSUB; kk++) {
            const float4 a = *(const float4*)&xs[kk * XSTR + tg * 4];
            const float av[4] = {a.x, a.y, a.z, a.w};
            #pragma unroll
            for (int q = 0; q < 4; q++) {
                const float4 w = ws4[kk * 16 + ng * 4 + q];  // uniform -> broadcast
                #pragma unroll
                for (int j = 0; j < 4; j++) {
                    acc[j*16 + q*4+0] = fmaf(av[j], w.x, acc[j*16 + q*4+0]);
                    acc[j*16 + q*4+1] = fmaf(av[j], w.y, acc[j*16 + q*4+1]);
                    acc[j*16 + q*4+2] = fmaf(av[j], w.z, acc[j*16 + q*4+2]);
                    acc[j*16 + q*4+3] = fmaf(av[j], w.w, acc[j*16 + q*4+3]);
                }
            }
        }
        __syncthreads();
    }
    // part[c][token][e]; consecutive e4 stores merge to full lines in L2
    #pragma unroll
    for (int j = 0; j < 4; j++) {
        float* dst = part + ((size_t)c * S + tb*256 + tg*4 + j) * E + ng*16;
        #pragma unroll
        for (int q = 0; q < 4; q++)
            *(float4*)(dst + q*4) = make_float4(acc[j*16+q*4+0], acc[j*16+q*4+1],
                                                acc[j*16+q*4+2], acc[j*16+q*4+3]);
    }
}

// ---------------- K1b: reduce partials, softmax, argmax, me atomics ----------
__global__ __launch_bounds__(256, 1)
void k1b_softmax(const float* __restrict__ part, float* __restrict__ gate_val,
                 int* __restrict__ idx1, int* __restrict__ counts,
                 float* __restrict__ me_sum) {
    const int tid = threadIdx.x, wv = tid >> 6, ln = tid & 63;
    const int token = blockIdx.x * 4 + wv;
    float p = 0.f;
    #pragma unroll
    for (int c = 0; c < CCH; c++) p += part[((size_t)c * S + token) * E + ln];
    // argmax (max value, lowest index on ties) — matches jnp.argmax
    float v = p; int i = ln;
    #pragma unroll
    for (int off = 1; off < 64; off <<= 1) {
        float ov = __shfl_xor(v, off, 64);
        int   oi = __shfl_xor(i, off, 64);
        if (ov > v || (ov == v && oi < i)) { v = ov; i = oi; }
    }
    float g = __expf(p - v);
    float ssum = g;
    #pragma unroll
    for (int off = 1; off < 64; off <<= 1) ssum += __shfl_xor(ssum, off, 64);
    const float gate = g / ssum;
    __shared__ float gs[4][64];
    gs[wv][ln] = gate;
    __syncthreads();
    if (tid < 64)
        atomicAdd(&me_sum[tid], gs[0][tid] + gs[1][tid] + gs[2][tid] + gs[3][tid]);
    if (ln == 0) {
        gate_val[token] = 1.0f / ssum;
        idx1[token] = i;
        atomicAdd(&counts[i], 1);
    }
}

// ---------------- K2: per-expert capacity selection + scatter ----------------
__device__ __forceinline__ int block_reduce_sum(int v, int* tmp4, int tid) {
    #pragma unroll
    for (int off = 1; off < 64; off <<= 1) v += __shfl_xor(v, off, 64);
    __syncthreads();
    if ((tid & 63) == 0) tmp4[tid >> 6] = v;
    __syncthreads();
    return tmp4[0] + tmp4[1] + tmp4[2] + tmp4[3];
}

__device__ __forceinline__ int block_scan_incl(int val, int* a, int* b, int tid, int* total) {
    __syncthreads();
    a[tid] = val;
    __syncthreads();
    int* src = a; int* dst = b;
    #pragma unroll
    for (int off = 1; off < 256; off <<= 1) {
        int v = src[tid];
        if (tid >= off) v += src[tid - off];
        dst[tid] = v;
        __syncthreads();
        int* t = src; src = dst; dst = t;
    }
    *total = src[255];
    return src[tid];
}

__global__ __launch_bounds__(256, 1)
void k2_select(const int* __restrict__ idx1, const float* __restrict__ gate_val,
               const float* __restrict__ noise, const int* __restrict__ counts,
               const float* __restrict__ me_sum, float* __restrict__ out) {
    const int e = blockIdx.x;
    const int tid = threadIdx.x;
    __shared__ int idx_s[S];
    __shared__ unsigned short l_tok[S];
    __shared__ float l_ns[S];
    __shared__ int sa[256], sb[256];
    __shared__ int tmp4[4];

    for (int i = tid; i < S; i += 256) idx_s[i] = idx1[i];
    __syncthreads();

    int cnt = 0;
    #pragma unroll
    for (int j4 = 0; j4 < 8; j4++) {
        const int4 q = *(const int4*)&idx_s[tid * 32 + j4 * 4];
        cnt += (q.x == e) + (q.y == e) + (q.z == e) + (q.w == e);
    }
    int total_n;
    int incl = block_scan_incl(cnt, sa, sb, tid, &total_n);
    int pos = incl - cnt;
    const int n = total_n;
    #pragma unroll
    for (int j4 = 0; j4 < 8; j4++) {
        const int4 q = *(const int4*)&idx_s[tid * 32 + j4 * 4];
        const int qv[4] = {q.x, q.y, q.z, q.w};
        #pragma unroll
        for (int u = 0; u < 4; u++) {
            const int s = tid * 32 + j4 * 4 + u;
            if (qv[u] == e) {
                l_tok[pos] = (unsigned short)s;
                l_ns[pos]  = noise[(size_t)s * E + e];
                pos++;
            }
        }
    }
    __syncthreads();

    if (tid == 0) out[EC_OFF + e] = (float)n;

    unsigned int V = 0u;
    if (n > CAP) {
        unsigned int lo = 0u, hi = 0x3F800000u;
        while (hi - lo > 1u) {
            const unsigned int mid = (lo + hi) >> 1;
            int c = 0;
            for (int i2 = tid; i2 < n; i2 += 256)
                c += (__float_as_uint(l_ns[i2]) >= mid);
            const int cge = block_reduce_sum(c, tmp4, tid);
            if (cge >= CAP) lo = mid; else hi = mid;
        }
        V = lo;
    }

    const int m = (n + 255) >> 8;
    const int i_begin = min(n, tid * m);
    const int i_end   = min(n, i_begin + m);
    int gt_l = 0, eq_l = 0;
    for (int i2 = i_begin; i2 < i_end; i2++) {
        const unsigned int b = __float_as_uint(l_ns[i2]);
        gt_l += (b > V); eq_l += (b == V);
    }
    int tot_gt, tot_eq;
    const int incl_gt = block_scan_incl(gt_l, sa, sb, tid, &tot_gt);
    (void)incl_gt;
    const int incl_eq = block_scan_incl(eq_l, sa, sb, tid, &tot_eq);
    const int eq_excl = incl_eq - eq_l;
    const int take_eq = CAP - tot_gt;   // ties -> lowest token index (jax top_k stable)
    const int sel_l = gt_l + max(0, min(eq_l, take_eq - eq_excl));
    int tot_sel;
    const int incl_sel = block_scan_incl(sel_l, sa, sb, tid, &tot_sel);
    int slot = incl_sel - sel_l;
    int eq_seen = eq_excl;
    for (int i2 = i_begin; i2 < i_end; i2++) {
        const unsigned int b = __float_as_uint(l_ns[i2]);
        bool sel;
        if (b > V) sel = true;
        else if (b == V) { sel = (eq_seen < take_eq); eq_seen++; }
        else sel = false;
        if (sel) {
            const int tok = l_tok[i2];
            const float g = gate_val[tok];
            const size_t off = (size_t)tok * (E * CAP) + (size_t)e * CAP + slot;
            out[CW_OFF + off] = g;
            out[DM_OFF + off] = 1.0f;
            slot++;
        }
    }

    if (e == 0 && tid < 64) {
        float la = (me_sum[tid] / (float)S) * ((float)counts[tid] / (float)S);
        #pragma unroll
        for (int off = 1; off < 64; off <<= 1) la += __shfl_xor(la, off, 64);
        if (tid == 0) out[0] = la * (float)E;
    }
}

extern "C" void kernel_launch(void* const* d_in, const int* in_sizes, int n_in,
                              void* d_out, int out_size, void* d_ws, size_t ws_size,
                              hipStream_t stream) {
    const float* x     = (const float*)d_in[0];
    const float* wg    = (const float*)d_in[1];
    const float* noise = (const float*)d_in[2];
    float* out = (float*)d_out;
    float* ws  = (float*)d_ws;

    float* gate_val = ws;                   // 8192 f32
    int*   idx1     = (int*)(ws + 8192);    // 8192 i32
    int*   counts   = (int*)(ws + 16384);   // 64 i32
    float* me_sum   = ws + 16448;           // 64 f32
    float* wt2      = ws + 16512;           // 262144 f32
    float* part     = ws + 16512 + 262144;  // 16*8192*64 f32 = 33.5 MB

    hipMemsetAsync(counts, 0, 128 * sizeof(int), stream);      // counts + me_sum
    hipMemsetAsync(out, 0, (size_t)out_size * sizeof(float), stream);
    k0_transpose<<<dim3(256),  dim3(256), 0, stream>>>(wg, wt2);
    k1_partial  <<<dim3(512),  dim3(256), 0, stream>>>(x, wt2, part);
    k1b_softmax <<<dim3(S/4),  dim3(256), 0, stream>>>(part, gate_val, idx1, counts, me_sum);
    k2_select   <<<dim3(E),    dim3(256), 0, stream>>>(idx1, gate_val, noise, counts, me_sum, out);
}

// Round 6
// 715.489 us; speedup vs baseline: 1.2977x; 1.0062x over previous
//
#include <hip/hip_runtime.h>

#define S    8192
#define Dm   4096
#define E    64
#define CAP  128
#define CCH  32          // split-K chunks
#define KC   (Dm/CCH)    // 128 k per chunk
#define KSUB 16          // k sub-tile staged in LDS
#define XSTR 260         // xs row stride: 16B-aligned, 2-way store conflicts (free)
#define WSTR 68          // ws row stride: 16B-aligned, 2-way store conflicts (free)

#define CW_OFF 1
#define DM_OFF (1 + (size_t)S*E*CAP)
#define EC_OFF (1 + 2*(size_t)S*E*CAP)

// ---------------- K1: register-tiled partial GEMM ---------------------------
// block: 256 tokens x 64 experts x KC k. thread: 8 tokens x 8 experts (acc[64]).
// Per kk per wave: 2 bank-balanced a-reads + 2 half-broadcast w-reads
// = ~24 LDS cyc per 128 SIMD-cyc of FMA; 16 waves/CU -> VALU-bound (~87% LDS).
__global__ __launch_bounds__(256, 4)
void k1_partial(const float* __restrict__ x, const float* __restrict__ wg,
                float* __restrict__ part) {
    __shared__ float xs[KSUB][XSTR];   // [k][token]
    __shared__ float ws[KSUB][WSTR];   // [k][e]
    const int tb  = blockIdx.x >> 5;   // 0..31 token block (256 tokens)
    const int c   = blockIdx.x & 31;   // 0..31 k chunk (128 k)
    const int tid = threadIdx.x;
    const int tt  = tid & 31;          // token group (8 tokens)
    const int ee  = tid >> 5;          // expert group (8 experts)
    const int k0  = c * KC;

    float acc[64];
    #pragma unroll
    for (int i = 0; i < 64; i++) acc[i] = 0.f;

    const int xr = tid >> 2;           // 0..63 token row base
    const int xc = tid & 3;            // float4 col within 16 k
    const int we = tid >> 2;           // 0..63 expert (W staging)
    const int wk = (tid & 3) * 4;      // k quad (W staging)

    for (int su = 0; su < KC / KSUB; su++) {
        const int ks0 = k0 + su * KSUB;
        // stage x: 256 tokens x 16 k, transposed into xs[k][token]
        #pragma unroll
        for (int i = 0; i < 4; i++) {
            const int row = i * 64 + xr;
            const float4 v = *(const float4*)(x + (size_t)(tb*256 + row) * Dm + ks0 + xc*4);
            xs[xc*4+0][row] = v.x;
            xs[xc*4+1][row] = v.y;
            xs[xc*4+2][row] = v.z;
            xs[xc*4+3][row] = v.w;
        }
        // stage W: 64 e x 16 k from wg, transposed into ws[k][e]
        {
            const float4 v = *(const float4*)(wg + (size_t)we * Dm + ks0 + wk);
            ws[wk+0][we] = v.x; ws[wk+1][we] = v.y;
            ws[wk+2][we] = v.z; ws[wk+3][we] = v.w;
        }
        __syncthreads();
        #pragma unroll 4
        for (int kk = 0; kk < KSUB; kk++) {
            const float4 a0 = *(const float4*)&xs[kk][tt*8];
            const float4 a1 = *(const float4*)&xs[kk][tt*8+4];
            const float4 w0 = *(const float4*)&ws[kk][ee*8];
            const float4 w1 = *(const float4*)&ws[kk][ee*8+4];
            const float av[8] = {a0.x,a0.y,a0.z,a0.w,a1.x,a1.y,a1.z,a1.w};
            const float wv[8] = {w0.x,w0.y,w0.z,w0.w,w1.x,w1.y,w1.z,w1.w};
            #pragma unroll
            for (int t = 0; t < 8; t++)
                #pragma unroll
                for (int e = 0; e < 8; e++)
                    acc[t*8+e] = fmaf(av[t], wv[e], acc[t*8+e]);
        }
        __syncthreads();
    }
    // part[c][token][e]
    #pragma unroll
    for (int t = 0; t < 8; t++) {
        float* dst = part + ((size_t)c * S + tb*256 + tt*8 + t) * E + ee*8;
        *(float4*)(dst)     = make_float4(acc[t*8+0], acc[t*8+1], acc[t*8+2], acc[t*8+3]);
        *(float4*)(dst + 4) = make_float4(acc[t*8+4], acc[t*8+5], acc[t*8+6], acc[t*8+7]);
    }
}

// ---------------- K1b: reduce partials, softmax, argmax, me atomics ----------
__global__ __launch_bounds__(256, 1)
void k1b_softmax(const float* __restrict__ part, float* __restrict__ gate_val,
                 int* __restrict__ idx1, int* __restrict__ counts,
                 float* __restrict__ me_sum) {
    const int tid = threadIdx.x, wv = tid >> 6, ln = tid & 63;
    const int token = blockIdx.x * 4 + wv;
    float p = 0.f;
    #pragma unroll
    for (int c = 0; c < CCH; c++) p += part[((size_t)c * S + token) * E + ln];
    // argmax (max value, lowest index on ties) — matches jnp.argmax
    float v = p; int i = ln;
    #pragma unroll
    for (int off = 1; off < 64; off <<= 1) {
        float ov = __shfl_xor(v, off, 64);
        int   oi = __shfl_xor(i, off, 64);
        if (ov > v || (ov == v && oi < i)) { v = ov; i = oi; }
    }
    float g = __expf(p - v);
    float ssum = g;
    #pragma unroll
    for (int off = 1; off < 64; off <<= 1) ssum += __shfl_xor(ssum, off, 64);
    const float gate = g / ssum;
    __shared__ float gs[4][64];
    gs[wv][ln] = gate;
    __syncthreads();
    if (tid < 64)
        atomicAdd(&me_sum[tid], gs[0][tid] + gs[1][tid] + gs[2][tid] + gs[3][tid]);
    if (ln == 0) {
        gate_val[token] = 1.0f / ssum;
        idx1[token] = i;
        atomicAdd(&counts[i], 1);
    }
}

// ---------------- K2: per-expert capacity selection + scatter ----------------
__device__ __forceinline__ int block_reduce_sum(int v, int* tmp4, int tid) {
    #pragma unroll
    for (int off = 1; off < 64; off <<= 1) v += __shfl_xor(v, off, 64);
    __syncthreads();
    if ((tid & 63) == 0) tmp4[tid >> 6] = v;
    __syncthreads();
    return tmp4[0] + tmp4[1] + tmp4[2] + tmp4[3];
}

__device__ __forceinline__ int block_scan_incl(int val, int* a, int* b, int tid, int* total) {
    __syncthreads();
    a[tid] = val;
    __syncthreads();
    int* src = a; int* dst = b;
    #pragma unroll
    for (int off = 1; off < 256; off <<= 1) {
        int v = src[tid];
        if (tid >= off) v += src[tid - off];
        dst[tid] = v;
        __syncthreads();
        int* t = src; src = dst; dst = t;
    }
    *total = src[255];
    return src[tid];
}

__global__ __launch_bounds__(256, 1)
void k2_select(const int* __restrict__ idx1, const float* __restrict__ gate_val,
               const float* __restrict__ noise, const int* __restrict__ counts,
               const float* __restrict__ me_sum, float* __restrict__ out) {
    const int e = blockIdx.x;
    const int tid = threadIdx.x;
    __shared__ int idx_s[S];
    __shared__ unsigned short l_tok[S];
    __shared__ float l_ns[S];
    __shared__ int sa[256], sb[256];
    __shared__ int tmp4[4];

    for (int i = tid; i < S; i += 256) idx_s[i] = idx1[i];
    __syncthreads();

    int cnt = 0;
    #pragma unroll
    for (int j4 = 0; j4 < 8; j4++) {
        const int4 q = *(const int4*)&idx_s[tid * 32 + j4 * 4];
        cnt += (q.x == e) + (q.y == e) + (q.z == e) + (q.w == e);
    }
    int total_n;
    int incl = block_scan_incl(cnt, sa, sb, tid, &total_n);
    int pos = incl - cnt;
    const int n = total_n;
    #pragma unroll
    for (int j4 = 0; j4 < 8; j4++) {
        const int4 q = *(const int4*)&idx_s[tid * 32 + j4 * 4];
        const int qv[4] = {q.x, q.y, q.z, q.w};
        #pragma unroll
        for (int u = 0; u < 4; u++) {
            const int s = tid * 32 + j4 * 4 + u;
            if (qv[u] == e) {
                l_tok[pos] = (unsigned short)s;
                l_ns[pos]  = noise[(size_t)s * E + e];
                pos++;
            }
        }
    }
    __syncthreads();

    if (tid == 0) out[EC_OFF + e] = (float)n;

    unsigned int V = 0u;
    if (n > CAP) {
        unsigned int lo = 0u, hi = 0x3F800000u;
        while (hi - lo > 1u) {
            const unsigned int mid = (lo + hi) >> 1;
            int c = 0;
            for (int i2 = tid; i2 < n; i2 += 256)
                c += (__float_as_uint(l_ns[i2]) >= mid);
            const int cge = block_reduce_sum(c, tmp4, tid);
            if (cge >= CAP) lo = mid; else hi = mid;
        }
        V = lo;
    }

    const int m = (n + 255) >> 8;
    const int i_begin = min(n, tid * m);
    const int i_end   = min(n, i_begin + m);
    int gt_l = 0, eq_l = 0;
    for (int i2 = i_begin; i2 < i_end; i2++) {
        const unsigned int b = __float_as_uint(l_ns[i2]);
        gt_l += (b > V); eq_l += (b == V);
    }
    int tot_gt, tot_eq;
    const int incl_gt = block_scan_incl(gt_l, sa, sb, tid, &tot_gt);
    (void)incl_gt;
    const int incl_eq = block_scan_incl(eq_l, sa, sb, tid, &tot_eq);
    const int eq_excl = incl_eq - eq_l;
    const int take_eq = CAP - tot_gt;   // ties -> lowest token index (jax top_k stable)
    const int sel_l = gt_l + max(0, min(eq_l, take_eq - eq_excl));
    int tot_sel;
    const int incl_sel = block_scan_incl(sel_l, sa, sb, tid, &tot_sel);
    int slot = incl_sel - sel_l;
    int eq_seen = eq_excl;
    for (int i2 = i_begin; i2 < i_end; i2++) {
        const unsigned int b = __float_as_uint(l_ns[i2]);
        bool sel;
        if (b > V) sel = true;
        else if (b == V) { sel = (eq_seen < take_eq); eq_seen++; }
        else sel = false;
        if (sel) {
            const int tok = l_tok[i2];
            const float g = gate_val[tok];
            const size_t off = (size_t)tok * (E * CAP) + (size_t)e * CAP + slot;
            out[CW_OFF + off] = g;
            out[DM_OFF + off] = 1.0f;
            slot++;
        }
    }

    if (e == 0 && tid < 64) {
        float la = (me_sum[tid] / (float)S) * ((float)counts[tid] / (float)S);
        #pragma unroll
        for (int off = 1; off < 64; off <<= 1) la += __shfl_xor(la, off, 64);
        if (tid == 0) out[0] = la * (float)E;
    }
}

extern "C" void kernel_launch(void* const* d_in, const int* in_sizes, int n_in,
                              void* d_out, int out_size, void* d_ws, size_t ws_size,
                              hipStream_t stream) {
    const float* x     = (const float*)d_in[0];
    const float* wg    = (const float*)d_in[1];
    const float* noise = (const float*)d_in[2];
    float* out = (float*)d_out;
    float* ws  = (float*)d_ws;

    float* gate_val = ws;                   // 8192 f32
    int*   idx1     = (int*)(ws + 8192);    // 8192 i32
    int*   counts   = (int*)(ws + 16384);   // 64 i32
    float* me_sum   = ws + 16448;           // 64 f32
    float* part     = ws + 16512;           // 32*8192*64 f32 = 67 MB

    hipMemsetAsync(counts, 0, 128 * sizeof(int), stream);      // counts + me_sum
    hipMemsetAsync(out, 0, (size_t)out_size * sizeof(float), stream);
    k1_partial  <<<dim3(1024), dim3(256), 0, stream>>>(x, wg, part);
    k1b_softmax <<<dim3(S/4),  dim3(256), 0, stream>>>(part, gate_val, idx1, counts, me_sum);
    k2_select   <<<dim3(E),    dim3(256), 0, stream>>>(idx1, gate_val, noise, counts, me_sum, out);
}